// Round 11
// baseline (229.123 us; speedup 1.0000x reference)
//
#include <hip/hip_runtime.h>

// GCN 2-layer for MI355X — INSTRUMENTATION ROUND (logic identical to r10).
// All 4 kernels are <41us and invisible under the harness poison fills in
// the top-5 dispatch table. Each kernel body is wrapped in an idempotent
// repeat loop (recompute identical outputs; memory-clobber between reps) to
// inflate its dispatch duration into the top-5: true T = dur / REP.
// REP_PART=3, REP_CSR=2, REP_AGG=4. Next round reverts the repeats.
//
// record: src (bits 0..16) | local_dst (bits 17..23), NPB=128

#define NPB    128
#define NBSH   7
#define NPART  512
#define PBS    1024
#define EPT    7
#define CAP    5120
#define CBS    1024
#define ABS    256
#define LPN    4

#define REP_PART 3
#define REP_CSR  2
#define REP_AGG  4

// ---- level 1: block-major bucket sort ----
__global__ __launch_bounds__(PBS) void k_part(
    const int* __restrict__ src, const int* __restrict__ dst,
    int E, int epb, int nbuck,
    int* __restrict__ offT, unsigned* __restrict__ packed)
{
    __shared__ int s_scan[PBS];
    __shared__ unsigned stage[PBS * EPT];
    const int b = blockIdx.x, t = threadIdx.x;
    const int lo = b * epb;
    int blockEdges = min(epb, E - lo); if (blockEdges < 0) blockEdges = 0;

    for (int rep = 0; rep < REP_PART; ++rep) {
        unsigned rec[EPT]; int bkt[EPT];
        s_scan[t] = 0;
        __syncthreads();
#pragma unroll
        for (int it = 0; it < EPT; ++it) {
            int idx = it * PBS + t;
            bkt[it] = -1; rec[it] = 0;
            if (idx < blockEdges) {
                int d = dst[lo + idx], s = src[lo + idx];
                rec[it] = (unsigned)s | ((unsigned)(d & (NPB - 1)) << 17);
                bkt[it] = d >> NBSH;
                atomicAdd(&s_scan[bkt[it]], 1);
            }
        }
        __syncthreads();
        int v = s_scan[t];
        for (int off = 1; off < PBS; off <<= 1) {
            __syncthreads();
            int a = (t >= off) ? s_scan[t - off] : 0;
            __syncthreads();
            s_scan[t] += a;
        }
        __syncthreads();
        int excl = s_scan[t] - v;
        __syncthreads();
        s_scan[t] = excl;
        if (t < nbuck) offT[(size_t)b * nbuck + t] = excl;
        __syncthreads();
#pragma unroll
        for (int it = 0; it < EPT; ++it)
            if (bkt[it] >= 0) {
                int pos = atomicAdd(&s_scan[bkt[it]], 1);
                stage[pos] = rec[it];
            }
        __syncthreads();
        for (int i = t; i < blockEdges; i += PBS)
            packed[(size_t)lo + i] = stage[i];
        __syncthreads();
        asm volatile("" ::: "memory");
    }
}

// ---- level 2: per-bucket node-level sort -> CSR + deg/dis/p1 fused ----
__global__ __launch_bounds__(CBS) void k_csr(
    const unsigned* __restrict__ packed, const int* __restrict__ offT,
    const float* __restrict__ x,
    int E, int epb, int nbuck, int n,
    unsigned* __restrict__ sorted, int* __restrict__ nstart, int* __restrict__ nend,
    float* __restrict__ dis, float* __restrict__ p1)
{
    __shared__ unsigned raw[CAP];
    __shared__ int offs[NPART], flen[NPART], fbase[NPART];
    __shared__ int cnt[NPB], cur[NPB];
    const int k = blockIdx.x, t = threadIdx.x;

    for (int rep = 0; rep < REP_CSR; ++rep) {
        if (t < NPART) {
            int o = offT[(size_t)t * nbuck + k];
            int e = (k + 1 < nbuck) ? offT[(size_t)t * nbuck + k + 1]
                                    : max(0, min(epb, E - t * epb));
            offs[t] = o; flen[t] = e - o;
            fbase[t] = e - o;
        }
        if (t < NPB) cnt[t] = 0;
        __syncthreads();
        for (int off = 1; off < NPART; off <<= 1) {
            __syncthreads();
            int a = (t >= off && t < NPART) ? fbase[t - off] : 0;
            __syncthreads();
            if (t < NPART) fbase[t] += a;
        }
        __syncthreads();
        int bsize = min(fbase[NPART - 1], CAP);
        __syncthreads();
        if (t < NPART) fbase[t] -= flen[t];
        __syncthreads();
        for (int fb = 0; fb < NPART; fb += (CBS >> 3)) {
            int f = fb + (t >> 3);
            if (f < NPART) {
                const unsigned* pp = packed + (size_t)f * epb + offs[f];
                int base = fbase[f], len = flen[f];
                for (int i = (t & 7); i < len; i += 8) {
                    int p = base + i;
                    if (p < CAP) raw[p] = pp[i];
                }
            }
        }
        __syncthreads();
        for (int i = t; i < bsize; i += CBS)
            atomicAdd(&cnt[raw[i] >> 17], 1);
        __syncthreads();
        if (t < NPB) cur[t] = cnt[t];
        for (int off = 1; off < NPB; off <<= 1) {
            __syncthreads();
            int a = (t >= off && t < NPB) ? cur[t - off] : 0;
            __syncthreads();
            if (t < NPB) cur[t] += a;
        }
        __syncthreads();
        if (t < NPB) {
            int deg = cnt[t];
            int excl = cur[t] - deg;
            cur[t] = excl;
            int d = k * NPB + t;
            if (d < n) {
                int st = k * CAP + excl;
                nstart[d] = st;
                nend[d]   = min(st + deg, (k + 1) * CAP);
                float r = rsqrtf((float)(deg + 1));
                dis[d] = r;
                p1[d]  = x[d] * r;
            }
        }
        __syncthreads();
        for (int i = t; i < bsize; i += CBS) {
            unsigned u = raw[i];
            int pos = k * CAP + atomicAdd(&cur[u >> 17], 1);
            sorted[pos] = u;
        }
        __syncthreads();
        asm volatile("" ::: "memory");
    }
}

// ---- layer 1: atomic-free segment reduce + fused MLP -> p2 ----
__global__ __launch_bounds__(ABS) void k_agg1(
    const unsigned* __restrict__ sorted,
    const int* __restrict__ nstart, const int* __restrict__ nend,
    const float* __restrict__ dis, const float* __restrict__ p1,
    const float* __restrict__ W1, const float* __restrict__ b1,
    const float* __restrict__ W2, int n, float2* __restrict__ p2)
{
    int gid = blockIdx.x * ABS + threadIdx.x;
    int d = gid >> 2, lane = gid & (LPN - 1);
    if (d >= n) return;
    for (int rep = 0; rep < REP_AGG; ++rep) {
        int s0 = nstart[d], e0 = nend[d];
        float acc = 0.f;
        int i = s0 + lane;
        for (; i + LPN < e0; i += 2 * LPN) {
            unsigned u1 = sorted[i];
            unsigned u2 = sorted[i + LPN];
            float g1 = __builtin_nontemporal_load(&p1[u1 & 0x1FFFFu]);
            float g2 = __builtin_nontemporal_load(&p1[u2 & 0x1FFFFu]);
            acc += g1 + g2;
        }
        if (i < e0) acc += __builtin_nontemporal_load(&p1[sorted[i] & 0x1FFFFu]);
        acc += __shfl_xor(acc, 1);
        acc += __shfl_xor(acc, 2);
        if (lane == 0) {
            float r   = dis[d];
            float agg = r * (acc + p1[d]);
            float c0 = 0.f, c1 = 0.f;
#pragma unroll
            for (int j = 0; j < 16; ++j) {
                float h = fmaxf(fmaf(agg, W1[j], b1[j]), 0.f);
                c0 = fmaf(h, W2[2 * j],     c0);
                c1 = fmaf(h, W2[2 * j + 1], c1);
            }
            p2[d] = make_float2(c0 * r, c1 * r);
        }
        asm volatile("" ::: "memory");
    }
}

// ---- layer 2: atomic-free segment reduce + fused log-softmax -> out ----
__global__ __launch_bounds__(ABS) void k_agg2(
    const unsigned* __restrict__ sorted,
    const int* __restrict__ nstart, const int* __restrict__ nend,
    const float* __restrict__ dis, const float2* __restrict__ p2,
    const float* __restrict__ b2, int n, float2* __restrict__ out)
{
    int gid = blockIdx.x * ABS + threadIdx.x;
    int d = gid >> 2, lane = gid & (LPN - 1);
    if (d >= n) return;
    for (int rep = 0; rep < REP_AGG; ++rep) {
        int s0 = nstart[d], e0 = nend[d];
        const double* p2d = (const double*)p2;
        float c0 = 0.f, c1 = 0.f;
        int i = s0 + lane;
        for (; i + LPN < e0; i += 2 * LPN) {
            unsigned u1 = sorted[i];
            unsigned u2 = sorted[i + LPN];
            double dv1 = __builtin_nontemporal_load(&p2d[u1 & 0x1FFFFu]);
            double dv2 = __builtin_nontemporal_load(&p2d[u2 & 0x1FFFFu]);
            float2 v1 = *(float2*)&dv1;
            float2 v2 = *(float2*)&dv2;
            c0 += v1.x + v2.x; c1 += v1.y + v2.y;
        }
        if (i < e0) {
            double dv = __builtin_nontemporal_load(&p2d[sorted[i] & 0x1FFFFu]);
            float2 v = *(float2*)&dv;
            c0 += v.x; c1 += v.y;
        }
        c0 += __shfl_xor(c0, 1);  c0 += __shfl_xor(c0, 2);
        c1 += __shfl_xor(c1, 1);  c1 += __shfl_xor(c1, 2);
        if (lane == 0) {
            float r = dis[d];
            float2 self = p2[d];
            float o0 = r * (c0 + self.x) + b2[0];
            float o1 = r * (c1 + self.y) + b2[1];
            float m  = fmaxf(o0, o1);
            float ls = m + logf(expf(o0 - m) + expf(o1 - m));
            out[d] = make_float2(o0 - ls, o1 - ls);
        }
        asm volatile("" ::: "memory");
    }
}

extern "C" void kernel_launch(void* const* d_in, const int* in_sizes, int n_in,
                              void* d_out, int out_size, void* d_ws, size_t ws_size,
                              hipStream_t stream) {
    const float* x  = (const float*)d_in[0];
    const int*   ei = (const int*)d_in[1];
    const float* W1 = (const float*)d_in[2];
    const float* b1 = (const float*)d_in[3];
    const float* W2 = (const float*)d_in[4];
    const float* b2 = (const float*)d_in[5];

    const int n = in_sizes[0];
    const int E = in_sizes[1] / 2;
    const int* src = ei;
    const int* dst = ei + E;

    const int nbuck = (n + NPB - 1) >> NBSH;
    const int epb   = (E + NPART - 1) / NPART;

    char* ws = (char*)d_ws;
    size_t off = 0;
    auto take = [&](size_t bytes) { char* p = ws + off; off += (bytes + 7) & ~(size_t)7; return p; };
    int*      offT   = (int*)take((size_t)NPART * nbuck * 4);
    unsigned* packed = (unsigned*)take((size_t)E * 4);
    unsigned* sorted = (unsigned*)take((size_t)nbuck * CAP * 4);
    int*      nstart = (int*)take((size_t)n * 4);
    int*      nend   = (int*)take((size_t)n * 4);
    float*    dis    = (float*)take((size_t)n * 4);
    float*    p1     = (float*)take((size_t)n * 4);
    float2*   p2     = (float2*)take((size_t)n * 8);

    const int gridAgg = ((size_t)n * LPN + ABS - 1) / ABS;

    k_part<<<NPART, PBS, 0, stream>>>(src, dst, E, epb, nbuck, offT, packed);
    k_csr <<<nbuck, CBS, 0, stream>>>(packed, offT, x, E, epb, nbuck, n,
                                      sorted, nstart, nend, dis, p1);
    k_agg1<<<gridAgg, ABS, 0, stream>>>(sorted, nstart, nend, dis, p1,
                                        W1, b1, W2, n, p2);
    k_agg2<<<gridAgg, ABS, 0, stream>>>(sorted, nstart, nend, dis, p2,
                                        b2, n, (float2*)d_out);
}

// Round 12
// 78.399 us; speedup vs baseline: 2.9225x; 2.9225x over previous
//
#include <hip/hip_runtime.h>

// GCN 2-layer for MI355X — two-level counting sort to per-node CSR, then
// atomic-free register-reduction aggregation.
// Round-11 instrumentation: part~22, csr~33, agg1~18, agg2~18, gaps~11.
// Round-12: csr at 4 blocks/CU (single wavefront of blocks), wave-shuffle
// scans everywhere (2 barriers instead of 14-20), agg LPN=8 with 4-wide
// unroll (one gather-latency chain per avg node), cached p1/p2 gathers.
//
// record: src (bits 0..16) | local_dst (bits 17..23), NPB=128

#define NPB    128
#define NBSH   7
#define NPART  512
#define PBS    1024     // k_part threads
#define EPT    7        // edges/thread in k_part (epb=6250 <= 7168)
#define CAP    5120     // per-bucket capacity (mean 4096, +16 sigma)
#define CBS    512      // k_csr threads -> 4 blocks/CU, 782 blocks in 1 round
#define ABS    256      // agg threads
#define LPN    8        // lanes per node in agg

// Block-wide exclusive scan via wave shuffles. NW = waves/block. Caller must
// barrier between consecutive uses (wsum is reused). Total ends in wsum[NW-1].
template <int NW>
__device__ __forceinline__ int block_exscan(int v, int t, int* wsum) {
    int lane = t & 63, wid = t >> 6;
    int inc = v;
#pragma unroll
    for (int off = 1; off < 64; off <<= 1) {
        int u = __shfl_up(inc, off);
        if (lane >= off) inc += u;
    }
    if (lane == 63) wsum[wid] = inc;
    __syncthreads();
    if (wid == 0) {
        int w = (lane < NW) ? wsum[lane] : 0;
#pragma unroll
        for (int off = 1; off < NW; off <<= 1) {
            int u = __shfl_up(w, off);
            if (lane >= off) w += u;
        }
        if (lane < NW) wsum[lane] = w;
    }
    __syncthreads();
    return inc - v + (wid ? wsum[wid - 1] : 0);
}

// ---- level 1: block-major bucket sort ----
__global__ __launch_bounds__(PBS) void k_part(
    const int* __restrict__ src, const int* __restrict__ dst,
    int E, int epb, int nbuck,
    int* __restrict__ offT, unsigned* __restrict__ packed)
{
    __shared__ int s_scan[PBS];
    __shared__ unsigned stage[PBS * EPT];
    __shared__ int wsum[PBS / 64];
    const int b = blockIdx.x, t = threadIdx.x;
    const int lo = b * epb;
    int blockEdges = min(epb, E - lo); if (blockEdges < 0) blockEdges = 0;

    unsigned rec[EPT]; int bkt[EPT];
    s_scan[t] = 0;
    __syncthreads();
#pragma unroll
    for (int it = 0; it < EPT; ++it) {
        int idx = it * PBS + t;
        bkt[it] = -1; rec[it] = 0;
        if (idx < blockEdges) {
            int d = dst[lo + idx], s = src[lo + idx];
            rec[it] = (unsigned)s | ((unsigned)(d & (NPB - 1)) << 17);
            bkt[it] = d >> NBSH;
            atomicAdd(&s_scan[bkt[it]], 1);
        }
    }
    __syncthreads();
    int v = s_scan[t];
    __syncthreads();
    int excl = block_exscan<PBS / 64>(v, t, wsum);
    s_scan[t] = excl;                          // reuse as cursors
    if (t < nbuck) offT[(size_t)b * nbuck + t] = excl;
    __syncthreads();
#pragma unroll
    for (int it = 0; it < EPT; ++it)
        if (bkt[it] >= 0) {
            int pos = atomicAdd(&s_scan[bkt[it]], 1);
            stage[pos] = rec[it];
        }
    __syncthreads();
    for (int i = t; i < blockEdges; i += PBS)
        packed[(size_t)lo + i] = stage[i];
}

// ---- level 2: per-bucket node-level sort -> CSR + deg/dis/p1 fused ----
__global__ __launch_bounds__(CBS) void k_csr(
    const unsigned* __restrict__ packed, const int* __restrict__ offT,
    const float* __restrict__ x,
    int E, int epb, int nbuck, int n,
    unsigned* __restrict__ sorted, int* __restrict__ nstart, int* __restrict__ nend,
    float* __restrict__ dis, float* __restrict__ p1)
{
    __shared__ unsigned raw[CAP];
    __shared__ int offs[NPART], fbase[NPART];
    __shared__ int cnt[NPB], cur[NPB];
    __shared__ int wsum[CBS / 64];
    __shared__ int s_bsize;
    const int k = blockIdx.x, t = threadIdx.x;

    // t indexes fragments 1:1 (CBS == NPART)
    int o = offT[(size_t)t * nbuck + k];
    int e = (k + 1 < nbuck) ? offT[(size_t)t * nbuck + k + 1]
                            : max(0, min(epb, E - t * epb));
    int myflen = e - o;
    offs[t] = o;
    if (t < NPB) cnt[t] = 0;
    __syncthreads();
    int fexcl = block_exscan<CBS / 64>(myflen, t, wsum);
    fbase[t] = fexcl;
    if (t == CBS - 1) s_bsize = min(fexcl + myflen, CAP);
    __syncthreads();
    const int bsize = s_bsize;
    // gather fragments into raw[]: 8 contiguous lanes per fragment
    for (int fb = 0; fb < NPART; fb += (CBS >> 3)) {
        int f = fb + (t >> 3);
        const unsigned* pp = packed + (size_t)f * epb + offs[f];
        int base = fbase[f];
        int len  = ((f + 1 < NPART) ? fbase[f + 1] : bsize) - base;
        for (int i = (t & 7); i < len; i += 8) {
            int p = base + i;
            if (p < CAP) raw[p] = pp[i];
        }
    }
    __syncthreads();
    // node-level count
    for (int i = t; i < bsize; i += CBS)
        atomicAdd(&cnt[raw[i] >> 17], 1);
    __syncthreads();
    int myc = (t < NPB) ? cnt[t] : 0;
    __syncthreads();
    int cexcl = block_exscan<CBS / 64>(myc, t, wsum);
    if (t < NPB) {
        cur[t] = cexcl;                        // cursor for scatter
        int d = k * NPB + t;
        if (d < n) {
            int st = k * CAP + cexcl;
            nstart[d] = st;
            nend[d]   = min(st + myc, (k + 1) * CAP);
            float r = rsqrtf((float)(myc + 1)); // +1 self-loop
            dis[d] = r;
            p1[d]  = x[d] * r;
        }
    }
    __syncthreads();
    // scatter into node-sorted order, coalesced contiguous region
    for (int i = t; i < bsize; i += CBS) {
        unsigned u = raw[i];
        int pos = k * CAP + atomicAdd(&cur[u >> 17], 1);
        sorted[pos] = u;
    }
}

// ---- layer 1: atomic-free segment reduce + fused MLP -> p2 ----
__global__ __launch_bounds__(ABS) void k_agg1(
    const unsigned* __restrict__ sorted,
    const int* __restrict__ nstart, const int* __restrict__ nend,
    const float* __restrict__ dis, const float* __restrict__ p1,
    const float* __restrict__ W1, const float* __restrict__ b1,
    const float* __restrict__ W2, int n, float2* __restrict__ p2)
{
    int gid = blockIdx.x * ABS + threadIdx.x;
    int d = gid >> 3, lane = gid & (LPN - 1);
    if (d >= n) return;
    int s0 = nstart[d], e0 = nend[d];
    float acc = 0.f;
    int i = s0 + lane;
    for (; i + 3 * LPN < e0; i += 4 * LPN) {   // 4 independent gathers in flight
        unsigned u0 = sorted[i];
        unsigned u1 = sorted[i + LPN];
        unsigned u2 = sorted[i + 2 * LPN];
        unsigned u3 = sorted[i + 3 * LPN];
        acc += p1[u0 & 0x1FFFFu] + p1[u1 & 0x1FFFFu]
             + p1[u2 & 0x1FFFFu] + p1[u3 & 0x1FFFFu];
    }
    for (; i < e0; i += LPN) acc += p1[sorted[i] & 0x1FFFFu];
    acc += __shfl_xor(acc, 1);
    acc += __shfl_xor(acc, 2);
    acc += __shfl_xor(acc, 4);
    if (lane == 0) {
        float r   = dis[d];
        float agg = r * (acc + p1[d]);          // + self-loop
        float c0 = 0.f, c1 = 0.f;
#pragma unroll
        for (int j = 0; j < 16; ++j) {
            float h = fmaxf(fmaf(agg, W1[j], b1[j]), 0.f);
            c0 = fmaf(h, W2[2 * j],     c0);
            c1 = fmaf(h, W2[2 * j + 1], c1);
        }
        p2[d] = make_float2(c0 * r, c1 * r);    // prescaled by dis[src]
    }
}

// ---- layer 2: atomic-free segment reduce + fused log-softmax -> out ----
__global__ __launch_bounds__(ABS) void k_agg2(
    const unsigned* __restrict__ sorted,
    const int* __restrict__ nstart, const int* __restrict__ nend,
    const float* __restrict__ dis, const float2* __restrict__ p2,
    const float* __restrict__ b2, int n, float2* __restrict__ out)
{
    int gid = blockIdx.x * ABS + threadIdx.x;
    int d = gid >> 3, lane = gid & (LPN - 1);
    if (d >= n) return;
    int s0 = nstart[d], e0 = nend[d];
    float c0 = 0.f, c1 = 0.f;
    int i = s0 + lane;
    for (; i + 3 * LPN < e0; i += 4 * LPN) {   // 4 gathers in flight
        float2 v0 = p2[sorted[i]           & 0x1FFFFu];
        float2 v1 = p2[sorted[i + LPN]     & 0x1FFFFu];
        float2 v2 = p2[sorted[i + 2 * LPN] & 0x1FFFFu];
        float2 v3 = p2[sorted[i + 3 * LPN] & 0x1FFFFu];
        c0 += v0.x + v1.x + v2.x + v3.x;
        c1 += v0.y + v1.y + v2.y + v3.y;
    }
    for (; i < e0; i += LPN) {
        float2 v = p2[sorted[i] & 0x1FFFFu];
        c0 += v.x; c1 += v.y;
    }
    c0 += __shfl_xor(c0, 1); c0 += __shfl_xor(c0, 2); c0 += __shfl_xor(c0, 4);
    c1 += __shfl_xor(c1, 1); c1 += __shfl_xor(c1, 2); c1 += __shfl_xor(c1, 4);
    if (lane == 0) {
        float r = dis[d];
        float2 self = p2[d];
        float o0 = r * (c0 + self.x) + b2[0];
        float o1 = r * (c1 + self.y) + b2[1];
        float m  = fmaxf(o0, o1);
        float ls = m + logf(expf(o0 - m) + expf(o1 - m));
        out[d] = make_float2(o0 - ls, o1 - ls);
    }
}

extern "C" void kernel_launch(void* const* d_in, const int* in_sizes, int n_in,
                              void* d_out, int out_size, void* d_ws, size_t ws_size,
                              hipStream_t stream) {
    const float* x  = (const float*)d_in[0];
    const int*   ei = (const int*)d_in[1];     // int32 [2, E]
    const float* W1 = (const float*)d_in[2];
    const float* b1 = (const float*)d_in[3];
    const float* W2 = (const float*)d_in[4];
    const float* b2 = (const float*)d_in[5];

    const int n = in_sizes[0];                 // 100000
    const int E = in_sizes[1] / 2;             // 3200000
    const int* src = ei;
    const int* dst = ei + E;

    const int nbuck = (n + NPB - 1) >> NBSH;   // 782
    const int epb   = (E + NPART - 1) / NPART; // 6250

    char* ws = (char*)d_ws;
    size_t off = 0;
    auto take = [&](size_t bytes) { char* p = ws + off; off += (bytes + 7) & ~(size_t)7; return p; };
    int*      offT   = (int*)take((size_t)NPART * nbuck * 4);     // 1.6 MB
    unsigned* packed = (unsigned*)take((size_t)E * 4);            // 12.8 MB
    unsigned* sorted = (unsigned*)take((size_t)nbuck * CAP * 4);  // 16 MB
    int*      nstart = (int*)take((size_t)n * 4);
    int*      nend   = (int*)take((size_t)n * 4);
    float*    dis    = (float*)take((size_t)n * 4);
    float*    p1     = (float*)take((size_t)n * 4);
    float2*   p2     = (float2*)take((size_t)n * 8);

    const int gridAgg = ((size_t)n * LPN + ABS - 1) / ABS;        // 3125

    k_part<<<NPART, PBS, 0, stream>>>(src, dst, E, epb, nbuck, offT, packed);
    k_csr <<<nbuck, CBS, 0, stream>>>(packed, offT, x, E, epb, nbuck, n,
                                      sorted, nstart, nend, dis, p1);
    k_agg1<<<gridAgg, ABS, 0, stream>>>(sorted, nstart, nend, dis, p1,
                                        W1, b1, W2, n, p2);
    k_agg2<<<gridAgg, ABS, 0, stream>>>(sorted, nstart, nend, dis, p2,
                                        b2, n, (float2*)d_out);
}